// Round 14
// baseline (229.131 us; speedup 1.0000x reference)
//
#include <hip/hip_runtime.h>
#include <hip/hip_cooperative_groups.h>

typedef unsigned short u16;
typedef unsigned int   u32;
typedef __attribute__((ext_vector_type(8))) short short8;   // 8 x bf16 (4 VGPRs)
typedef __attribute__((ext_vector_type(16))) float f32x16;

#define MFMA32(a, b, c) __builtin_amdgcn_mfma_f32_32x32x16_bf16(a, b, c, 0, 0, 0)

constexpr int Lv = 2048, Hv = 8, Ev = 64, HE = Hv * Ev; // HE=512
constexpr float QSCALE = 0.18033688011112042f;          // 0.125 * log2(e)
constexpr size_t WSV_OFF = 32u * 64u * 2048u;           // u16 offset of V images
// ws layout: K plain bf16 [bh][key 0..2047][e 0..63] (8 MB), then V images
// [bh*64+tg][2048 u16] (8 MB).
#define WS_NEED ((size_t)16777216)

__device__ __forceinline__ float bf2f(u16 u) {
    u32 x = ((u32)u) << 16;
    return __builtin_bit_cast(float, x);
}
__device__ __forceinline__ u16 f2bf(float f) {   // RNE, finite inputs
    u32 x = __builtin_bit_cast(u32, f);
    u32 r = ((x >> 16) & 1u) + 0x7fffu;
    return (u16)((x + r) >> 16);
}
__device__ __forceinline__ u32 pkbf(float a, float b) {
#if __has_builtin(__builtin_amdgcn_cvt_pk_bf16_f32)
    typedef __attribute__((ext_vector_type(2))) __bf16 bf16x2;
    bf16x2 v = __builtin_amdgcn_cvt_pk_bf16_f32(a, b);
    return __builtin_bit_cast(u32, v);
#else
    return (u32)f2bf(a) | ((u32)f2bf(b) << 16);
#endif
}
__device__ __forceinline__ float fexp2(float x) {
#if __has_builtin(__builtin_amdgcn_exp2f)
    return __builtin_amdgcn_exp2f(x);
#else
    return exp2f(x);
#endif
}

// async global(16B/lane) -> LDS(base + lane*16). Guide §5 / m97 pattern.
__device__ __forceinline__ void gll16(const void* g, void* l) {
    __builtin_amdgcn_global_load_lds(
        (const __attribute__((address_space(1))) void*)g,
        (__attribute__((address_space(3))) void*)l, 16, 0, 0);
}

// Runtime dtype sniff (validated rounds 0-13: fp32 inputs detected correctly).
__device__ __forceinline__ int detect_isbf16(const u32* q32, int lane) {
    u32 w0 = q32[2 * lane];
    u32 w1 = q32[2 * lane + 1];
    u16 uu[4] = { (u16)(w0 & 0xffff), (u16)(w0 >> 16),
                  (u16)(w1 & 0xffff), (u16)(w1 >> 16) };
    int p = 0, z = 0;
#pragma unroll
    for (int j = 0; j < 4; ++j) {
        u16 mgn = (u16)(uu[j] & 0x7fff);
        int ex  = mgn >> 7;
        bool zero = (mgn == 0);
        bool pl   = zero || (ex >= 115 && ex <= 132);
        p += pl ? 1 : 0;
        if ((j & 1) == 0) z += zero ? 1 : 0;
    }
    int acc = p | (z << 16);
#pragma unroll
    for (int o = 1; o < 64; o <<= 1) acc += __shfl_xor(acc, o);
    int ps = acc & 0xffff, zs = acc >> 16;
    if (zs >= 100) return 0;
    return (ps >= 240) ? 1 : 0;
}

__device__ __forceinline__ short8 cvt8s(const float* p, float s) {
    float4 a = *(const float4*)p, b4 = *(const float4*)(p + 4);
    u32 r[4] = { pkbf(a.x * s, a.y * s), pkbf(a.z * s, a.w * s),
                 pkbf(b4.x * s, b4.y * s), pkbf(b4.z * s, b4.w * s) };
    return *(short8*)r;
}

__device__ __forceinline__ f32x16 zv16() {
    f32x16 z;
#pragma unroll
    for (int r = 0; r < 16; ++r) z[r] = 0.f;
    return z;
}

// Exchange a.hi-lanes <-> b.lo-lanes (v_permlane32_swap_b32 semantics).
__device__ __forceinline__ void plswap(u32& a, u32& b) {
#if __has_builtin(__builtin_amdgcn_permlane32_swap)
    auto r = __builtin_amdgcn_permlane32_swap(a, b, false, false);
    a = r[0]; b = r[1];
#else
    int lane = (int)(threadIdx.x & 63);
    u32 ax = (u32)__shfl_xor((int)a, 32);
    u32 bx = (u32)__shfl_xor((int)b, 32);
    bool hi = lane >= 32;
    u32 na = hi ? bx : a;
    u32 nb = hi ? b  : ax;
    a = na; b = nb;
#endif
}

// ---------------------------------------------------------------------------
// V image layout (unchanged from rounds 10-13):
//   addr a: e=a>>5, sf=(a&31)>>3, j=a&7, key=((sf^((e+(e>>3))&3))<<3)+j
// K is now stored PLAIN (bf16 cast of source rows); the old K-image swizzle
// is folded into GLLK's per-lane global source address (m173: gll source is
// per-lane, dest stays linear).
// ---------------------------------------------------------------------------

// Convert work for ONE tile (32 keys), executed by NT threads (tl < NT).
template <int ISBF, int NT>
__device__ __forceinline__ void conv_tile(const void* kin, const void* vin,
                                          size_t inb, int tg,
                                          u16* __restrict__ kdst,
                                          u16* __restrict__ vimg,
                                          u16* __restrict__ VTt, int tl) {
    // ---- K plain copy: 2048 u16 per tile, 16B granules ----
#pragma unroll
    for (int r = 0; r < 2048 / (8 * NT); ++r) {
        int a = 8 * (tl + NT * r);         // 0..2040
        int key = a >> 6, e0 = a & 63;
        size_t s = inb + (size_t)(tg * 32 + key) * HE + e0;
        if (ISBF) {
            *(uint4*)&kdst[a] = *(const uint4*)((const u16*)kin + s);
        } else {
            float4 p0 = *(const float4*)((const float*)kin + s);
            float4 p1 = *(const float4*)((const float*)kin + s + 4);
            uint4 v; v.x = pkbf(p0.x, p0.y); v.y = pkbf(p0.z, p0.w);
                     v.z = pkbf(p1.x, p1.y); v.w = pkbf(p1.z, p1.w);
            *(uint4*)&kdst[a] = v;
        }
    }
    // ---- V rows -> VTt[key*72 + e], coalesced reads ----
#pragma unroll
    for (int r = 0; r < 512 / NT; ++r) {
        int f = tl + NT * r;               // 0..511
        int key = f >> 4, part = f & 15;
        size_t src = inb + (size_t)(tg * 32 + key) * HE + part * 4;
        if (ISBF) {
            uint2 vv_ = *(const uint2*)((const u16*)vin + src);
            *(uint2*)&VTt[key * 72 + part * 4] = vv_;
        } else {
            float4 v = *(const float4*)((const float*)vin + src);
            uint2 pv; pv.x = pkbf(v.x, v.y); pv.y = pkbf(v.z, v.w);
            *(uint2*)&VTt[key * 72 + part * 4] = pv;
        }
    }
    __syncthreads();
    // ---- V image: 8B coalesced writes; LDS absorbs the scatter ----
#pragma unroll
    for (int r = 0; r < 512 / NT; ++r) {
        int idx = tl + NT * r;             // 0..511
        int a = 4 * idx;
        int e = a >> 5, sf = (a & 31) >> 3, j0 = a & 7;
        int m = (e + (e >> 3)) & 3;
        int k0 = ((sf ^ m) << 3) + j0;
        uint2 val;
        val.x = (u32)VTt[k0 * 72 + e]       | ((u32)VTt[(k0 + 1) * 72 + e] << 16);
        val.y = (u32)VTt[(k0 + 2) * 72 + e] | ((u32)VTt[(k0 + 3) * 72 + e] << 16);
        *(uint2*)&vimg[a] = val;
    }
}

// Standalone convert kernel (two-kernel fallback path). 2048 blocks x 256.
template <int ISBF>
__device__ __forceinline__ void convert_impl(const void* kin, const void* vin,
                                             u16* __restrict__ ws, u16* VT) {
    const int blk = blockIdx.x;            // bh*64 + tg
    const int bh  = blk >> 6, tg = blk & 63;
    const int b   = bh >> 3,  h  = bh & 7;
    const size_t inb = (size_t)b * Lv * HE + h * Ev;
    u16* kdst = ws + ((size_t)bh * 2048 + (size_t)tg * 32) * 64;
    u16* vimg = ws + WSV_OFF + ((size_t)bh * 64 + tg) * 2048;
    conv_tile<ISBF, 256>(kin, vin, inb, tg, kdst, vimg, VT, threadIdx.x);
}

__global__ __launch_bounds__(256) void convert_kernel(
    const void* __restrict__ qv, const void* __restrict__ kv,
    const void* __restrict__ vv, u16* __restrict__ ws)
{
    __shared__ u16 VT[32 * 72];            // 4.5 KB transpose tile
    const int isbf = detect_isbf16((const u32*)qv, threadIdx.x & 63);
    if (isbf) convert_impl<1>(kv, vv, ws, VT);
    else      convert_impl<0>(kv, vv, ws, VT);
}

// Fused convert phase: block fid converts the 4 tiles (tg = rb*4+tt) of its
// OWN bh (16 blocks/bh x 4 tiles = all 64 tiles). 4 tiles in parallel,
// 128 threads each; VT tiles live in the (not-yet-used) attn SMEM.
template <int ISBF>
__device__ __forceinline__ void convert_phase(const void* kin, const void* vin,
                                              u16* __restrict__ ws, u16* SMEM) {
    const int fid = blockIdx.x;
    const int bh  = (fid & 7) * 4 + ((fid >> 3) & 3);
    const int rb  = fid >> 5;
    const int t   = threadIdx.x;           // 0..511
    const int tt  = t >> 7, tl = t & 127;
    const int tg  = rb * 4 + tt;
    const int b   = bh >> 3, h = bh & 7;
    const size_t inb = (size_t)b * Lv * HE + h * Ev;
    u16* kdst = ws + ((size_t)bh * 2048 + (size_t)tg * 32) * 64;
    u16* vimg = ws + WSV_OFF + ((size_t)bh * 64 + tg) * 2048;
    u16* VTt  = SMEM + tt * 2304;          // 4 x 4.5 KB = 18 KB
    conv_tile<ISBF, 128>(kin, vin, inb, tg, kdst, vimg, VTt, tl);
    __syncthreads();                       // VT region dead before attn reuse
}

// ---------------------------------------------------------------------------
// Fused full attention + l=0 local blend.  Attn body frozen since round 12
// (63.7 us proven; VGPR 64+64 = exactly the 128/wave budget). Only change:
// K is read from the PLAIN bf16 copy with the swizzle folded into the gll
// per-lane SOURCE address (identical bytes land in ldsK; QK_ unchanged).
// Barrier-free K-loop, wave-private 8 KB LDS, att[2], counted vmcnt.
// WS=0 fallback: round-10 direct-staging path, unchanged.
// ---------------------------------------------------------------------------
template <int ISBF, int WS>
__device__ __forceinline__ void attn_impl(
    const void* __restrict__ qv, const void* __restrict__ kv,
    const void* __restrict__ vv, const void* __restrict__ alphav,
    void* __restrict__ outv, const u16* __restrict__ ws, u16* SMEM)
{
    const int tid  = threadIdx.x;       // 0..511
    const int w    = tid >> 6;          // wave 0..7
    const int lane = tid & 63;
    const int l31  = lane & 31;
    const int hi   = lane >> 5;
    const int qg   = w & 3;             // query sub-block (32 rows)
    const int g    = w >> 2;            // key-half group (1024 keys)

    // XCD-aware mapping: xcd = fid&7 handles bh in {4*xcd .. 4*xcd+3}.
    const int fid = blockIdx.x;         // 0..511
    const int bh  = (fid & 7) * 4 + ((fid >> 3) & 3);
    const int rb  = fid >> 5;           // 0..15
    const int b   = bh >> 3, h = bh & 7;
    const int row0 = rb * 128;

    const size_t bhoff = (size_t)b * Lv * HE + h * Ev;
    const u16*   q16 = (const u16*)qv + bhoff;
    const u16*   k16 = (const u16*)kv + bhoff;
    const u16*   v16 = (const u16*)vv + bhoff;
    const float* q32 = (const float*)qv + bhoff;
    const float* k32 = (const float*)kv + bhoff;
    const float* v32 = (const float*)vv + bhoff;

    // wave-private LDS slice: K tile [32 key][64 e] + V tile [64 e][32 key]
    u16* ldsK = SMEM + w * 4096;
    u16* ldsV = ldsK + 2048;

    // Q fragments (pre-scaled). qf[c][j] = Qs[row0+qg*32+l31][16c+8hi+j].
    short8 qf[4];
    {
        size_t ro = (size_t)(row0 + qg * 32 + l31) * HE + hi * 8;
        if (ISBF) {
#pragma unroll
            for (int c = 0; c < 4; ++c) {
                short8 t = *(const short8*)(q16 + ro + 16 * c);
#pragma unroll
                for (int j = 0; j < 8; ++j)
                    qf[c][j] = (short)f2bf(bf2f((u16)t[j]) * QSCALE);
            }
        } else {
#pragma unroll
            for (int c = 0; c < 4; ++c) qf[c] = cvt8s(q32 + ro + 16 * c, QSCALE);
        }
    }

    f32x16 O[2];
    O[0] = zv16(); O[1] = zv16();
    f32x16 StA = zv16(), StB = zv16();   // att[2] ping-pong score states
    float psum = 0.f;

    // WS=1 bases: K plain rows for this g; V image tiles tg = g*32 + kt.
    const u16* kimg0 = ws + ((size_t)bh * 2048 + (size_t)g * 1024) * 64;
    const u16* vimg0 = ws + WSV_OFF + ((size_t)bh * 64 + g * 32) * 2048;
    // per-lane K source offset: key=(lane>>3), e0=((lane&7)^(key&7))*8
    const int klaneoff = (lane >> 3) * 64 + (((lane & 7) ^ ((lane >> 3) & 7)) << 3);
    const size_t keybase = (size_t)g * 1024;     // WS=0 global key offset

    // WS=0 staging lane mapping
    const int k0l = lane >> 3;
    const int kj  = lane & 7;
    const int e0K = ((kj ^ k0l) << 3);
    const int eoV = kj * 8;

    // WS=0 prefetch registers
    float4 fpa, fpb, fpc, fpd;
    uint4  upa, upb;

    // ---------------- WS=1 gll staging ----------------
#define GLLK(KT) do {                                                          \
        const u16* ib_ = kimg0 + (size_t)(KT) * 2048 + klaneoff;               \
        _Pragma("unroll")                                                      \
        for (int s_ = 0; s_ < 4; ++s_)                                         \
            gll16(ib_ + s_ * 512, ldsK + s_ * 512);                            \
    } while (0)
#define GLLV(KT) do {                                                          \
        const u16* ib_ = vimg0 + (size_t)(KT) * 2048 + lane * 8;               \
        _Pragma("unroll")                                                      \
        for (int s_ = 0; s_ < 4; ++s_)                                         \
            gll16(ib_ + s_ * 512, ldsV + s_ * 512);                            \
    } while (0)
#define WAITV4() do { asm volatile("s_waitcnt vmcnt(4)" ::: "memory");         \
        __builtin_amdgcn_sched_barrier(0); } while (0)
#define WAITV0() do { asm volatile("s_waitcnt vmcnt(0)" ::: "memory");         \
        __builtin_amdgcn_sched_barrier(0); } while (0)
#define WAITL0() do { asm volatile("s_waitcnt lgkmcnt(0)" ::: "memory");       \
        __builtin_amdgcn_sched_barrier(0); } while (0)

    // ---------------- WS=0 staging (round-10, unchanged) ----------------
#define LK0(KT, CH) do {                                                       \
        size_t tb_ = (keybase + (size_t)(KT) * 32) * HE;                       \
        int key_ = (CH) * 16 + k0l;                                            \
        if (ISBF) {                                                            \
            const u16* p_ = k16 + tb_ + (size_t)key_ * HE + e0K;               \
            upa = *(const uint4*)p_;                                           \
            upb = *(const uint4*)(p_ + 8 * HE);                                \
        } else {                                                               \
            const float* p_ = k32 + tb_ + (size_t)key_ * HE + e0K;             \
            fpa = *(const float4*)p_;            fpb = *(const float4*)(p_ + 4);\
            fpc = *(const float4*)(p_ + 8 * HE); fpd = *(const float4*)(p_ + 8 * HE + 4);\
        }                                                                      \
    } while (0)
#define SK0(CH) do {                                                           \
        if (ISBF) {                                                            \
            *(uint4*)&ldsK[((CH)*2    ) * 512 + lane * 8] = upa;               \
            *(uint4*)&ldsK[((CH)*2 + 1) * 512 + lane * 8] = upb;               \
        } else {                                                               \
            u32 t0_[4] = { pkbf(fpa.x, fpa.y), pkbf(fpa.z, fpa.w),             \
                           pkbf(fpb.x, fpb.y), pkbf(fpb.z, fpb.w) };           \
            u32 t1_[4] = { pkbf(fpc.x, fpc.y), pkbf(fpc.z, fpc.w),             \
                           pkbf(fpd.x, fpd.y), pkbf(fpd.z, fpd.w) };           \
            *(uint4*)&ldsK[((CH)*2    ) * 512 + lane * 8] = *(uint4*)t0_;      \
            *(uint4*)&ldsK[((CH)*2 + 1) * 512 + lane * 8] = *(uint4*)t1_;      \
        }                                                                      \
    } while (0)
#define LV0(KT, VH) do {                                                       \
        size_t tb_ = (keybase + (size_t)(KT) * 32 + (VH) * 16 + 2 * k0l) * HE; \
        if (ISBF) {                                                            \
            const u16* p_ = v16 + tb_ + eoV;                                   \
            upa = *(const uint4*)p_;                                           \
            upb = *(const uint4*)(p_ + HE);                                    \
        } else {                                                               \
            const float* p_ = v32 + tb_ + eoV;                                 \
            fpa = *(const float4*)p_;       fpb = *(const float4*)(p_ + 4);    \
            fpc = *(const float4*)(p_ + HE); fpd = *(const float4*)(p_ + HE + 4);\
        }                                                                      \
    } while (0)
#define SV0(VH) do {                                                           \
        int s_ = (k0l >> 2) + (VH) * 2;                                        \
        if (ISBF) {                                                            \
            const u16* a0_ = (const u16*)&upa;                                 \
            const u16* a1_ = (const u16*)&upb;                                 \
            _Pragma("unroll")                                                  \
            for (int j = 0; j < 8; ++j) {                                      \
                int e_ = eoV + j;                                              \
                int sl_ = s_ ^ ((e_ + (e_ >> 3)) & 3);                         \
                *(u32*)&ldsV[e_ * 32 + sl_ * 8 + ((2 * k0l) & 7)] =            \
                    (u32)a0_[j] | ((u32)a1_[j] << 16);                         \
            }                                                                  \
        } else {                                                               \
            float t0_[8] = {fpa.x, fpa.y, fpa.z, fpa.w, fpb.x, fpb.y, fpb.z, fpb.w};\
            float t1_[8] = {fpc.x, fpc.y, fpc.z, fpc.w, fpd.x, fpd.y, fpd.z, fpd.w};\
            _Pragma("unroll")                                                  \
            for (int j = 0; j < 8; ++j) {                                      \
                int e_ = eoV + j;                                              \
                int sl_ = s_ ^ ((e_ + (e_ >> 3)) & 3);                         \
                *(u32*)&ldsV[e_ * 32 + sl_ * 8 + ((2 * k0l) & 7)] =            \
                    pkbf(t0_[j], t1_[j]);                                      \
            }                                                                  \
        }                                                                      \
    } while (0)

    // ---------------- compute macros ----------------
#define QK_(ST) do {                                                           \
        (ST) = zv16();                                                         \
        __builtin_amdgcn_s_setprio(1);                                         \
        _Pragma("unroll")                                                      \
        for (int c = 0; c < 4; ++c) {                                          \
            int sl = (2 * c + hi) ^ (l31 & 7);                                 \
            short8 kf = *(const short8*)&ldsK[l31 * 64 + sl * 8];              \
            (ST) = MFMA32(kf, qf[c], (ST));                                    \
        }                                                                      \
        __builtin_amdgcn_s_setprio(0);                                         \
    } while (0)

    u32 c8[8];
#define SM_(SP) do {                                                           \
        _Pragma("unroll")                                                      \
        for (int r = 0; r < 16; ++r) (SP)[r] = fexp2((SP)[r]);                 \
        _Pragma("unroll")                                                      \
        for (int r = 0; r < 16; ++r) psum += (SP)[r];                          \
        _Pragma("unroll")                                                      \
        for (int q = 0; q < 8; ++q) c8[q] = pkbf((SP)[2 * q], (SP)[2 * q + 1]);\
    } while (0)

#define PV_(T) do {                                                            \
        u32 a0 = c8[4 * (T) + 0], a1 = c8[4 * (T) + 1];                        \
        u32 a2 = c8[4 * (T) + 2], a3 = c8[4 * (T) + 3];                        \
        plswap(a0, a2);                                                        \
        plswap(a1, a3);                                                        \
        u32 pw_[4] = { a0, a1, a2, a3 };                                       \
        short8 pa = *(short8*)pw_;                                             \
        __builtin_amdgcn_s_setprio(1);                                         \
        _Pragma("unroll")                                                      \
        for (int et = 0; et < 2; ++et) {                                       \
            int e  = et * 32 + l31;                                            \
            int sl = (2 * (T) + hi) ^ ((e + (e >> 3)) & 3);                    \
            short8 vf = *(const short8*)&ldsV[e * 32 + sl * 8];                \
            O[et] = MFMA32(pa, vf, O[et]);                                     \
        }                                                                      \
        __builtin_amdgcn_s_setprio(0);                                         \
    } while (0)

    // att[2] steady-state body: QK(KT)->SC || SM(SP = tile KT-1 scores);
    // then PV(tile KT-1). gll windows: K(KT+1) lands under PV + next A;
    // V(KT) lands under next region A.
#define BODY(KT, SC, SP) do {                                                  \
        WAITV4();              /* K(KT) landed; V(KT-1) still in flight */     \
        QK_(SC);               /* region A: MFMA/LDS stream             */     \
        SM_(SP);               /*           + independent VALU stream   */     \
        WAITL0();              /* QK ds_reads retired (SM has no ds)    */     \
        GLLK((KT) + 1);                                                        \
        WAITV4();              /* V(KT-1) landed; K(KT+1) stays out     */     \
        PV_(0);                                                                \
        PV_(1);                /* region B: tile KT-1                   */     \
        WAITL0();              /* PV ds_reads retired                   */     \
        GLLV(KT);                                                              \
    } while (0)

    // ---------------- barrier-free K-loop ----------------
    if (WS) {
        // prologue: tile 0 into ldsK; FIFO at BODY(1) top = [K1, V0]
        GLLK(0);
        WAITV0();
        QK_(StA);              // scores of tile 0
        WAITL0();
        GLLK(1);
        GLLV(0);
        // kt = 1..30: odd -> SC=StB, even -> SC=StA
        for (int j = 0; j < 15; ++j) {
            const int kt = 2 * j + 1;
            BODY(kt,     StB, StA);
            BODY(kt + 1, StA, StB);
        }
        // kt = 31 (no GLLK(32))
        WAITV4();              // K31 landed
        QK_(StB);
        SM_(StA);              // tile 30 scores
        WAITL0();
        WAITV0();              // V30 landed
        PV_(0);
        PV_(1);                // tile 30
        WAITL0();
        GLLV(31);
        WAITV0();              // V31 landed
        SM_(StB);              // tile 31
        PV_(0);
        PV_(1);
    } else {
        LK0(0, 0); SK0(0); LK0(0, 1); SK0(1);
        LV0(0, 0); SV0(0); LV0(0, 1); SV0(1);
        for (int kt = 0; kt < 32; ++kt) {
            if (kt < 31) LK0(kt + 1, 0);
            QK_(StA);
            if (kt < 31) { SK0(0); LK0(kt + 1, 1); }
            SM_(StA);
            if (kt < 31) { SK0(1); LV0(kt + 1, 0); }
            PV_(0);
            if (kt < 31) { SV0(0); LV0(kt + 1, 1); }
            PV_(1);
            if (kt < 31) SV0(1);
        }
    }
#undef GLLK
#undef GLLV
#undef WAITV4
#undef WAITV0
#undef WAITL0
#undef LK0
#undef SK0
#undef LV0
#undef SV0
#undef QK_
#undef SM_
#undef PV_
#undef BODY

    // ---- combine the two key-halves through LDS (exact, unnormalized) ----
    __syncthreads();                              // all waves done with tiles
    float pst = psum + __shfl_xor(psum, 32);      // row sum over this half
    float* cb = (float*)SMEM;                     // tiles dead; reuse as f32
    const int cbase = qg * 2368 + lane * 36;      // 36 f32 stride: 16B-aligned

    if (g == 1) {
        union { f32x16 v; float4 q4[4]; } u;
        u.v = O[0];
#pragma unroll
        for (int i = 0; i < 4; ++i) *(float4*)&cb[cbase + 4 * i] = u.q4[i];
        u.v = O[1];
#pragma unroll
        for (int i = 0; i < 4; ++i) *(float4*)&cb[cbase + 16 + 4 * i] = u.q4[i];
        cb[qg * 2368 + 2304 + lane] = pst;
    }

    // ---- l=0 local attention (wave 0 = qg0/g0 of rb==0 blocks) ----
    float locv[2] = {0.f, 0.f};
    float wgt = 0.f;
    const bool w0blk = (rb == 0) && (w == 0);
    if (w0blk) {
        const int e = lane;
        const size_t base = bhoff + e;
#define LDIN(p, i) (ISBF ? bf2f(((const u16*)(p))[i]) : ((const float*)(p))[i])
        float qe = LDIN(qv, base);
        float s[9];
#pragma unroll
        for (int j = 0; j < 9; ++j) {
            float prod = qe * LDIN(kv, base + (size_t)j * HE);
#pragma unroll
            for (int o = 1; o < 64; o <<= 1) prod += __shfl_xor(prod, o);
            s[j] = prod * 0.125f;
        }
        float mx = s[0];
#pragma unroll
        for (int j = 1; j < 9; ++j) mx = fmaxf(mx, s[j]);
        float we[9];
#pragma unroll
        for (int j = 0; j < 9; ++j) we[j] = expf(s[j] - mx);
        float denom = 9.f * we[0];
        float acc   = 9.f * we[0] * LDIN(vv, base);
#pragma unroll
        for (int j = 1; j < 9; ++j) {
            denom += we[j];
            acc   += we[j] * LDIN(vv, base + (size_t)j * HE);
        }
        float loc = acc / denom;

        float a;
        if (ISBF) {
            a = bf2f(((const u16*)alphav)[0]);
            if (!(a >= 0.0f && a <= 1.0f)) {
                float af = ((const float*)alphav)[0];
                if (af >= 0.0f && af <= 1.0f) a = af;
            }
        } else {
            a = ((const float*)alphav)[0];
            if (!(a >= 0.0f && a <= 1.0f)) {
                float ab = bf2f(((const u16*)alphav)[0]);
                if (ab >= 0.0f && ab <= 1.0f) a = ab;
            }
        }
        wgt = 1.f / (1.f + expf(-a));
#pragma unroll
        for (int et = 0; et < 2; ++et) locv[et] = __shfl(loc, et * 32 + l31);
#undef LDIN
    }

    __syncthreads();                              // partials visible
    if (g != 0) return;

    // ---- g==0 waves: add partner partials, normalize, blend, store ----
    float pstp = cb[qg * 2368 + 2304 + lane];
#pragma unroll
    for (int r = 0; r < 16; ++r) {
        O[0][r] += cb[cbase + r];
        O[1][r] += cb[cbase + 16 + r];
    }
    float invv = 1.0f / (pst + pstp);

#pragma unroll
    for (int rg = 0; rg < 4; ++rg) {
#pragma unroll
        for (int rr = 0; rr < 4; ++rr) {
            const int reg = rg * 4 + rr;
            const int rl  = rr + 8 * rg + 4 * hi;       // local output row
            float inv = __shfl(invv, rl);               // broadcast from lane rl
            int row = row0 + qg * 32 + rl;
            size_t oo = (size_t)(b * Lv + row) * HE + h * Ev + l31;
            bool blend = w0blk && (rl == 0);
#pragma unroll
            for (int et = 0; et < 2; ++et) {
                float res = O[et][reg] * inv;
                if (blend) res = wgt * res + (1.f - wgt) * locv[et];
                if (ISBF) ((u16*)outv)[oo + et * 32] = f2bf(res);
                else      ((float*)outv)[oo + et * 32] = res;
            }
        }
    }
}

// ---------------- FUSED kernel: convert + grid sync + attn ----------------
__global__ __launch_bounds__(512, 4) void fused_kernel(
    const void* __restrict__ qv, const void* __restrict__ kv,
    const void* __restrict__ vv, const void* __restrict__ alphav,
    void* __restrict__ outv, u16* __restrict__ ws)
{
    __shared__ u16 SMEM[32768];   // convert VT (18 KB) first, then attn tiles
    const int isbf = detect_isbf16((const u32*)qv, threadIdx.x & 63);
    if (isbf) convert_phase<1>(kv, vv, ws, SMEM);
    else      convert_phase<0>(kv, vv, ws, SMEM);
    cooperative_groups::this_grid().sync();
    if (isbf) attn_impl<1, 1>(qv, kv, vv, alphav, outv, ws, SMEM);
    else      attn_impl<0, 1>(qv, kv, vv, alphav, outv, ws, SMEM);
}

__global__ __launch_bounds__(512, 4) void attn_kernel_ws(
    const void* __restrict__ qv, const void* __restrict__ kv,
    const void* __restrict__ vv, const void* __restrict__ alphav,
    void* __restrict__ outv, const u16* __restrict__ ws)
{
    __shared__ u16 SMEM[32768];
    const int isbf = detect_isbf16((const u32*)qv, threadIdx.x & 63);
    if (isbf) attn_impl<1, 1>(qv, kv, vv, alphav, outv, ws, SMEM);
    else      attn_impl<0, 1>(qv, kv, vv, alphav, outv, ws, SMEM);
}

__global__ __launch_bounds__(512, 4) void attn_kernel_nws(
    const void* __restrict__ qv, const void* __restrict__ kv,
    const void* __restrict__ vv, const void* __restrict__ alphav,
    void* __restrict__ outv)
{
    __shared__ u16 SMEM[32768];
    const int isbf = detect_isbf16((const u32*)qv, threadIdx.x & 63);
    if (isbf) attn_impl<1, 0>(qv, kv, vv, alphav, outv, nullptr, SMEM);
    else      attn_impl<0, 0>(qv, kv, vv, alphav, outv, nullptr, SMEM);
}

extern "C" void kernel_launch(void* const* d_in, const int* in_sizes, int n_in,
                              void* d_out, int out_size, void* d_ws, size_t ws_size,
                              hipStream_t stream) {
    if (d_ws != nullptr && ws_size >= WS_NEED) {
        void* q  = d_in[0]; void* k = d_in[1]; void* v = d_in[2];
        void* al = d_in[3]; void* o = d_out;  void* w = d_ws;
        void* kargs[6] = { &q, &k, &v, &al, &o, &w };
        hipError_t e = hipLaunchCooperativeKernel(
            reinterpret_cast<void*>(fused_kernel), dim3(512), dim3(512),
            kargs, 0, stream);
        if (e == hipSuccess) return;
        (void)hipGetLastError();          // clear; fall back to two-kernel
        hipLaunchKernelGGL(convert_kernel, dim3(2048), dim3(256), 0, stream,
                           d_in[0], d_in[1], d_in[2], (u16*)d_ws);
        hipLaunchKernelGGL(attn_kernel_ws, dim3(512), dim3(512), 0, stream,
                           d_in[0], d_in[1], d_in[2], d_in[3], d_out,
                           (const u16*)d_ws);
    } else {
        hipLaunchKernelGGL(attn_kernel_nws, dim3(512), dim3(512), 0, stream,
                           d_in[0], d_in[1], d_in[2], d_in[3], d_out);
    }
}

// Round 15
// 183.888 us; speedup vs baseline: 1.2460x; 1.2460x over previous
//
#include <hip/hip_runtime.h>

typedef unsigned short u16;
typedef unsigned int   u32;
typedef __attribute__((ext_vector_type(8))) short short8;   // 8 x bf16 (4 VGPRs)
typedef __attribute__((ext_vector_type(16))) float f32x16;

#define MFMA32(a, b, c) __builtin_amdgcn_mfma_f32_32x32x16_bf16(a, b, c, 0, 0, 0)

constexpr int Lv = 2048, Hv = 8, Ev = 64, HE = Hv * Ev; // HE=512
constexpr float QSCALE = 0.18033688011112042f;          // 0.125 * log2(e)

__device__ __forceinline__ float bf2f(u16 u) {
    u32 x = ((u32)u) << 16;
    return __builtin_bit_cast(float, x);
}
__device__ __forceinline__ u16 f2bf(float f) {   // RNE, finite inputs
    u32 x = __builtin_bit_cast(u32, f);
    u32 r = ((x >> 16) & 1u) + 0x7fffu;
    return (u16)((x + r) >> 16);
}
__device__ __forceinline__ u32 pkbf(float a, float b) {
#if __has_builtin(__builtin_amdgcn_cvt_pk_bf16_f32)
    typedef __attribute__((ext_vector_type(2))) __bf16 bf16x2;
    bf16x2 v = __builtin_amdgcn_cvt_pk_bf16_f32(a, b);
    return __builtin_bit_cast(u32, v);
#else
    return (u32)f2bf(a) | ((u32)f2bf(b) << 16);
#endif
}
__device__ __forceinline__ float fexp2(float x) {
#if __has_builtin(__builtin_amdgcn_exp2f)
    return __builtin_amdgcn_exp2f(x);
#else
    return exp2f(x);
#endif
}

// Runtime dtype sniff (validated rounds 0-14: fp32 inputs detected correctly).
__device__ __forceinline__ int detect_isbf16(const u32* q32, int lane) {
    u32 w0 = q32[2 * lane];
    u32 w1 = q32[2 * lane + 1];
    u16 uu[4] = { (u16)(w0 & 0xffff), (u16)(w0 >> 16),
                  (u16)(w1 & 0xffff), (u16)(w1 >> 16) };
    int p = 0, z = 0;
#pragma unroll
    for (int j = 0; j < 4; ++j) {
        u16 mgn = (u16)(uu[j] & 0x7fff);
        int ex  = mgn >> 7;
        bool zero = (mgn == 0);
        bool pl   = zero || (ex >= 115 && ex <= 132);
        p += pl ? 1 : 0;
        if ((j & 1) == 0) z += zero ? 1 : 0;
    }
    int acc = p | (z << 16);
#pragma unroll
    for (int o = 1; o < 64; o <<= 1) acc += __shfl_xor(acc, o);
    int ps = acc & 0xffff, zs = acc >> 16;
    if (zs >= 100) return 0;
    return (ps >= 240) ? 1 : 0;
}

__device__ __forceinline__ short8 cvt8s(const float* p, float s) {
    float4 a = *(const float4*)p, b4 = *(const float4*)(p + 4);
    u32 r[4] = { pkbf(a.x * s, a.y * s), pkbf(a.z * s, a.w * s),
                 pkbf(b4.x * s, b4.y * s), pkbf(b4.z * s, b4.w * s) };
    return *(short8*)r;
}

__device__ __forceinline__ f32x16 zv16() {
    f32x16 z;
#pragma unroll
    for (int r = 0; r < 16; ++r) z[r] = 0.f;
    return z;
}

// Exchange a.hi-lanes <-> b.lo-lanes (v_permlane32_swap_b32 semantics).
__device__ __forceinline__ void plswap(u32& a, u32& b) {
#if __has_builtin(__builtin_amdgcn_permlane32_swap)
    auto r = __builtin_amdgcn_permlane32_swap(a, b, false, false);
    a = r[0]; b = r[1];
#else
    int lane = (int)(threadIdx.x & 63);
    u32 ax = (u32)__shfl_xor((int)a, 32);
    u32 bx = (u32)__shfl_xor((int)b, 32);
    bool hi = lane >= 32;
    u32 na = hi ? bx : a;
    u32 nb = hi ? b  : ax;
    a = na; b = nb;
#endif
}

// ---------------------------------------------------------------------------
// Fused full attention + l=0 local blend.  Round-15: SINGLE kernel,
// barrier-free, DIRECT staging (the unmeasured quadrant).
//   * No convert kernel, no ws, no second launch (R12-14 measured the
//     two-kernel tax at ~14.5 us system time; R14 killed grid-sync fusion).
//   * Barrier-free wave-private loop (R10: -10 us vs barrier convoy).
//     512 blocks x 512 thr; wave = (qg: 32 queries) x (g: 1024 keys);
//     8 KB private LDS slice/wave (K [32key][64e] + V [64e][32key],
//     single-buffered: same-wave LDS ops are program-ordered, so
//     store(kt+1)-after-read(kt) is safe with no sync).
//   * Direct global->reg->cvt->swizzled-LDS staging interleaved with
//     compute (R10 WS=0 structure, math re-verified; R11 measured staging
//     issue-count as off-the-critical-path).
//   * Single St (no att[2]): keeps fp32 staging transients within the
//     128 reg/wave budget (R9/R12 lesson: att[2]+prefetch regs spill).
//   * K/V reads are 16x redundant across blocks of one bh but L2-resident
//     (4 bh x 1 MB fp32 = 4 MB/XCD = L2 size); XCD-aware bh mapping.
// Split-K halves combined through LDS at the end (exact, unnormalized).
// ---------------------------------------------------------------------------
template <int ISBF>
__device__ __forceinline__ void attn_impl(
    const void* __restrict__ qv, const void* __restrict__ kv,
    const void* __restrict__ vv, const void* __restrict__ alphav,
    void* __restrict__ outv, u16* SMEM)
{
    const int tid  = threadIdx.x;       // 0..511
    const int w    = tid >> 6;          // wave 0..7
    const int lane = tid & 63;
    const int l31  = lane & 31;
    const int hi   = lane >> 5;
    const int qg   = w & 3;             // query sub-block (32 rows)
    const int g    = w >> 2;            // key-half group (1024 keys)

    // XCD-aware mapping: xcd = fid&7 handles bh in {4*xcd .. 4*xcd+3}.
    const int fid = blockIdx.x;         // 0..511
    const int bh  = (fid & 7) * 4 + ((fid >> 3) & 3);
    const int rb  = fid >> 5;           // 0..15
    const int b   = bh >> 3, h = bh & 7;
    const int row0 = rb * 128;

    const size_t bhoff = (size_t)b * Lv * HE + h * Ev;
    const u16*   q16 = (const u16*)qv + bhoff;
    const u16*   k16 = (const u16*)kv + bhoff;
    const u16*   v16 = (const u16*)vv + bhoff;
    const float* q32 = (const float*)qv + bhoff;
    const float* k32 = (const float*)kv + bhoff;
    const float* v32 = (const float*)vv + bhoff;

    // wave-private LDS slice: K tile [32 key][64 e] + V tile [64 e][32 key]
    u16* ldsK = SMEM + w * 4096;
    u16* ldsV = ldsK + 2048;

    // Q fragments (pre-scaled). qf[c][j] = Qs[row0+qg*32+l31][16c+8hi+j].
    short8 qf[4];
    {
        size_t ro = (size_t)(row0 + qg * 32 + l31) * HE + hi * 8;
        if (ISBF) {
#pragma unroll
            for (int c = 0; c < 4; ++c) {
                short8 t = *(const short8*)(q16 + ro + 16 * c);
#pragma unroll
                for (int j = 0; j < 8; ++j)
                    qf[c][j] = (short)f2bf(bf2f((u16)t[j]) * QSCALE);
            }
        } else {
#pragma unroll
            for (int c = 0; c < 4; ++c) qf[c] = cvt8s(q32 + ro + 16 * c, QSCALE);
        }
    }

    f32x16 O[2];
    O[0] = zv16(); O[1] = zv16();
    float psum = 0.f;

    const size_t keybase = (size_t)g * 1024;     // this wave's key offset

    // staging lane mapping (R10 WS=0, re-verified):
    // K: lane covers keys {CH*16 + k0l, +8}; source e-offset e0K folds the
    //    slot swizzle into the GLOBAL address; LDS writes are linear.
    // V: lane covers key pair (2*k0l, 2*k0l+1) at e-octet eoV; LDS writes
    //    scattered per the [e][key] slot swizzle.
    const int k0l = lane >> 3;          // 0..7
    const int kj  = lane & 7;
    const int e0K = ((kj ^ k0l) << 3);
    const int eoV = kj * 8;

    // staging transient registers
    float4 fpa, fpb, fpc, fpd;          // fp32 path
    uint4  upa, upb;                    // bf16 path

#define LK0(KT, CH) do {                                                       \
        size_t tb_ = (keybase + (size_t)(KT) * 32) * HE;                       \
        int key_ = (CH) * 16 + k0l;                                            \
        if (ISBF) {                                                            \
            const u16* p_ = k16 + tb_ + (size_t)key_ * HE + e0K;               \
            upa = *(const uint4*)p_;                                           \
            upb = *(const uint4*)(p_ + 8 * HE);                                \
        } else {                                                               \
            const float* p_ = k32 + tb_ + (size_t)key_ * HE + e0K;             \
            fpa = *(const float4*)p_;            fpb = *(const float4*)(p_ + 4);\
            fpc = *(const float4*)(p_ + 8 * HE); fpd = *(const float4*)(p_ + 8 * HE + 4);\
        }                                                                      \
    } while (0)
#define SK0(CH) do {                                                           \
        if (ISBF) {                                                            \
            *(uint4*)&ldsK[((CH)*2    ) * 512 + lane * 8] = upa;               \
            *(uint4*)&ldsK[((CH)*2 + 1) * 512 + lane * 8] = upb;               \
        } else {                                                               \
            u32 t0_[4] = { pkbf(fpa.x, fpa.y), pkbf(fpa.z, fpa.w),             \
                           pkbf(fpb.x, fpb.y), pkbf(fpb.z, fpb.w) };           \
            u32 t1_[4] = { pkbf(fpc.x, fpc.y), pkbf(fpc.z, fpc.w),             \
                           pkbf(fpd.x, fpd.y), pkbf(fpd.z, fpd.w) };           \
            *(uint4*)&ldsK[((CH)*2    ) * 512 + lane * 8] = *(uint4*)t0_;      \
            *(uint4*)&ldsK[((CH)*2 + 1) * 512 + lane * 8] = *(uint4*)t1_;      \
        }                                                                      \
    } while (0)
#define LV0(KT, VH) do {                                                       \
        size_t tb_ = (keybase + (size_t)(KT) * 32 + (VH) * 16 + 2 * k0l) * HE; \
        if (ISBF) {                                                            \
            const u16* p_ = v16 + tb_ + eoV;                                   \
            upa = *(const uint4*)p_;                                           \
            upb = *(const uint4*)(p_ + HE);                                    \
        } else {                                                               \
            const float* p_ = v32 + tb_ + eoV;                                 \
            fpa = *(const float4*)p_;       fpb = *(const float4*)(p_ + 4);    \
            fpc = *(const float4*)(p_ + HE); fpd = *(const float4*)(p_ + HE + 4);\
        }                                                                      \
    } while (0)
#define SV0(VH) do {                                                           \
        int s_ = (k0l >> 2) + (VH) * 2;                                        \
        if (ISBF) {                                                            \
            const u16* a0_ = (const u16*)&upa;                                 \
            const u16* a1_ = (const u16*)&upb;                                 \
            _Pragma("unroll")                                                  \
            for (int j = 0; j < 8; ++j) {                                      \
                int e_ = eoV + j;                                              \
                int sl_ = s_ ^ ((e_ + (e_ >> 3)) & 3);                         \
                *(u32*)&ldsV[e_ * 32 + sl_ * 8 + ((2 * k0l) & 7)] =            \
                    (u32)a0_[j] | ((u32)a1_[j] << 16);                         \
            }                                                                  \
        } else {                                                               \
            float t0_[8] = {fpa.x, fpa.y, fpa.z, fpa.w, fpb.x, fpb.y, fpb.z, fpb.w};\
            float t1_[8] = {fpc.x, fpc.y, fpc.z, fpc.w, fpd.x, fpd.y, fpd.z, fpd.w};\
            _Pragma("unroll")                                                  \
            for (int j = 0; j < 8; ++j) {                                      \
                int e_ = eoV + j;                                              \
                int sl_ = s_ ^ ((e_ + (e_ >> 3)) & 3);                         \
                *(u32*)&ldsV[e_ * 32 + sl_ * 8 + ((2 * k0l) & 7)] =            \
                    pkbf(t0_[j], t1_[j]);                                      \
            }                                                                  \
        }                                                                      \
    } while (0)

    // ---------------- compute macros ----------------
    f32x16 St;
#define QK_() do {                                                             \
        St = zv16();                                                           \
        __builtin_amdgcn_s_setprio(1);                                         \
        _Pragma("unroll")                                                      \
        for (int c = 0; c < 4; ++c) {                                          \
            int sl = (2 * c + hi) ^ (l31 & 7);                                 \
            short8 kf = *(const short8*)&ldsK[l31 * 64 + sl * 8];              \
            St = MFMA32(kf, qf[c], St);                                        \
        }                                                                      \
        __builtin_amdgcn_s_setprio(0);                                         \
    } while (0)

    u32 c8[8];
#define SM_() do {                                                             \
        _Pragma("unroll")                                                      \
        for (int r = 0; r < 16; ++r) St[r] = fexp2(St[r]);                     \
        _Pragma("unroll")                                                      \
        for (int r = 0; r < 16; ++r) psum += St[r];                            \
        _Pragma("unroll")                                                      \
        for (int q = 0; q < 8; ++q) c8[q] = pkbf(St[2 * q], St[2 * q + 1]);    \
    } while (0)

#define PV_(T) do {                                                            \
        u32 a0 = c8[4 * (T) + 0], a1 = c8[4 * (T) + 1];                        \
        u32 a2 = c8[4 * (T) + 2], a3 = c8[4 * (T) + 3];                        \
        plswap(a0, a2);                                                        \
        plswap(a1, a3);                                                        \
        u32 pw_[4] = { a0, a1, a2, a3 };                                       \
        short8 pa = *(short8*)pw_;                                             \
        __builtin_amdgcn_s_setprio(1);                                         \
        _Pragma("unroll")                                                      \
        for (int et = 0; et < 2; ++et) {                                       \
            int e  = et * 32 + l31;                                            \
            int sl = (2 * (T) + hi) ^ ((e + (e >> 3)) & 3);                    \
            short8 vf = *(const short8*)&ldsV[e * 32 + sl * 8];                \
            O[et] = MFMA32(pa, vf, O[et]);                                     \
        }                                                                      \
        __builtin_amdgcn_s_setprio(0);                                         \
    } while (0)

    // ---------------- barrier-free K-loop (R10 WS=0 schedule) ----------------
    // Same-wave LDS program order makes interleaved staging safe:
    //   SK0(0) after QK_ (reads of kt retired before chunks 0-1 overwritten)
    //   SV0(0) after PV_(0) (keys 0..15 read before overwrite), etc.
    LK0(0, 0); SK0(0); LK0(0, 1); SK0(1);
    LV0(0, 0); SV0(0); LV0(0, 1); SV0(1);
    for (int kt = 0; kt < 32; ++kt) {
        if (kt < 31) LK0(kt + 1, 0);
        QK_();
        if (kt < 31) { SK0(0); LK0(kt + 1, 1); }
        SM_();
        if (kt < 31) { SK0(1); LV0(kt + 1, 0); }
        PV_(0);                             // reads V keys 0..15 of kt
        if (kt < 31) { SV0(0); LV0(kt + 1, 1); }
        PV_(1);                             // reads V keys 16..31 of kt
        if (kt < 31) SV0(1);
    }
#undef LK0
#undef SK0
#undef LV0
#undef SV0
#undef QK_
#undef SM_
#undef PV_

    // ---- combine the two key-halves through LDS (exact, unnormalized) ----
    __syncthreads();                              // all waves done with tiles
    float pst = psum + __shfl_xor(psum, 32);      // row sum over this half
    float* cb = (float*)SMEM;                     // tiles dead; reuse as f32
    const int cbase = qg * 2368 + lane * 36;      // 36 f32 stride: 16B-aligned

    if (g == 1) {
        union { f32x16 v; float4 q4[4]; } u;
        u.v = O[0];
#pragma unroll
        for (int i = 0; i < 4; ++i) *(float4*)&cb[cbase + 4 * i] = u.q4[i];
        u.v = O[1];
#pragma unroll
        for (int i = 0; i < 4; ++i) *(float4*)&cb[cbase + 16 + 4 * i] = u.q4[i];
        cb[qg * 2368 + 2304 + lane] = pst;
    }

    // ---- l=0 local attention (wave 0 = qg0/g0 of rb==0 blocks) ----
    float locv[2] = {0.f, 0.f};
    float wgt = 0.f;
    const bool w0blk = (rb == 0) && (w == 0);
    if (w0blk) {
        const int e = lane;
        const size_t base = bhoff + e;
#define LDIN(p, i) (ISBF ? bf2f(((const u16*)(p))[i]) : ((const float*)(p))[i])
        float qe = LDIN(qv, base);
        float s[9];
#pragma unroll
        for (int j = 0; j < 9; ++j) {
            float prod = qe * LDIN(kv, base + (size_t)j * HE);
#pragma unroll
            for (int o = 1; o < 64; o <<= 1) prod += __shfl_xor(prod, o);
            s[j] = prod * 0.125f;
        }
        float mx = s[0];
#pragma unroll
        for (int j = 1; j < 9; ++j) mx = fmaxf(mx, s[j]);
        float we[9];
#pragma unroll
        for (int j = 0; j < 9; ++j) we[j] = expf(s[j] - mx);
        float denom = 9.f * we[0];
        float acc   = 9.f * we[0] * LDIN(vv, base);
#pragma unroll
        for (int j = 1; j < 9; ++j) {
            denom += we[j];
            acc   += we[j] * LDIN(vv, base + (size_t)j * HE);
        }
        float loc = acc / denom;

        float a;
        if (ISBF) {
            a = bf2f(((const u16*)alphav)[0]);
            if (!(a >= 0.0f && a <= 1.0f)) {
                float af = ((const float*)alphav)[0];
                if (af >= 0.0f && af <= 1.0f) a = af;
            }
        } else {
            a = ((const float*)alphav)[0];
            if (!(a >= 0.0f && a <= 1.0f)) {
                float ab = bf2f(((const u16*)alphav)[0]);
                if (ab >= 0.0f && ab <= 1.0f) a = ab;
            }
        }
        wgt = 1.f / (1.f + expf(-a));
#pragma unroll
        for (int et = 0; et < 2; ++et) locv[et] = __shfl(loc, et * 32 + l31);
#undef LDIN
    }

    __syncthreads();                              // partials visible
    if (g != 0) return;

    // ---- g==0 waves: add partner partials, normalize, blend, store ----
    float pstp = cb[qg * 2368 + 2304 + lane];
#pragma unroll
    for (int r = 0; r < 16; ++r) {
        O[0][r] += cb[cbase + r];
        O[1][r] += cb[cbase + 16 + r];
    }
    float invv = 1.0f / (pst + pstp);

#pragma unroll
    for (int rg = 0; rg < 4; ++rg) {
#pragma unroll
        for (int rr = 0; rr < 4; ++rr) {
            const int reg = rg * 4 + rr;
            const int rl  = rr + 8 * rg + 4 * hi;       // local output row
            float inv = __shfl(invv, rl);               // broadcast from lane rl
            int row = row0 + qg * 32 + rl;
            size_t oo = (size_t)(b * Lv + row) * HE + h * Ev + l31;
            bool blend = w0blk && (rl == 0);
#pragma unroll
            for (int et = 0; et < 2; ++et) {
                float res = O[et][reg] * inv;
                if (blend) res = wgt * res + (1.f - wgt) * locv[et];
                if (ISBF) ((u16*)outv)[oo + et * 32] = f2bf(res);
                else      ((float*)outv)[oo + et * 32] = res;
            }
        }
    }
}

__global__ __launch_bounds__(512, 4) void attn_kernel(
    const void* __restrict__ qv, const void* __restrict__ kv,
    const void* __restrict__ vv, const void* __restrict__ alphav,
    void* __restrict__ outv)
{
    // 64 KB: 8 waves x (K tile 4 KB + V tile 4 KB), wave-private.
    // Reused as float scratch (9472 f32) for split-K combine at the end.
    __shared__ u16 SMEM[32768];
    const int isbf = detect_isbf16((const u32*)qv, threadIdx.x & 63);
    if (isbf) attn_impl<1>(qv, kv, vv, alphav, outv, SMEM);
    else      attn_impl<0>(qv, kv, vv, alphav, outv, SMEM);
}

extern "C" void kernel_launch(void* const* d_in, const int* in_sizes, int n_in,
                              void* d_out, int out_size, void* d_ws, size_t ws_size,
                              hipStream_t stream) {
    hipLaunchKernelGGL(attn_kernel, dim3(512), dim3(512), 0, stream,
                       d_in[0], d_in[1], d_in[2], d_in[3], d_out);
}